// Round 1
// baseline (4660.894 us; speedup 1.0000x reference)
//
#include <hip/hip_runtime.h>
#include <hip/hip_bf16.h>

// PGN decoder: B=32, L=400, T=40 steps, H=A=512, E=256, V=32000, oov=50.
// Outputs (flat in d_out, fp32): final (40,32,32050) | attns (40,32,400) |
// covs (40,32,400) | h_f (32,512) | ctx_f (32,512) | pgens (40,32)
#define BB 32
#define LL 400
#define TT 40
#define HH 512
#define VV 32000
#define VEXT 32050

typedef __attribute__((ext_vector_type(8))) short bf16x8;
typedef __attribute__((ext_vector_type(4))) float f32x4;

__device__ __forceinline__ float bf2f(unsigned short u){
  union { unsigned int i; float f; } v; v.i = ((unsigned int)u) << 16; return v.f;
}
__device__ __forceinline__ unsigned short f2bf(float f){
  union { float f; unsigned int i; } v; v.f = f;
  unsigned int i = v.i;
  return (unsigned short)((i + 0x7FFFu + ((i >> 16) & 1u)) >> 16); // RNE
}
__device__ __forceinline__ float fast_tanh(float x){
  x = fminf(20.f, fmaxf(-20.f, x));
  float e = __expf(2.f * x);
  return (e - 1.f) * __builtin_amdgcn_rcpf(e + 1.f);
}
__device__ __forceinline__ float fast_sigmoid(float x){
  x = fminf(30.f, fmaxf(-30.f, x));
  return __builtin_amdgcn_rcpf(1.f + __expf(-x));
}

// ---------------- P0: weight transposes (f32 -> bf16 NxK) + converts ----------------
__device__ void transpose_bf16(const float* __restrict__ in, unsigned short* __restrict__ out,
                               int R, int C, int tile, float (*t)[65]){
  int tcn = C >> 6;
  int tr = tile / tcn, tc = tile - tr * tcn;
  int r0 = tr << 6, c0 = tc << 6;
  int cc = threadIdx.x & 63, rb = threadIdx.x >> 6;
  #pragma unroll
  for (int p = 0; p < 16; p++){
    int r = rb + p * 4;
    t[r][cc] = in[(size_t)(r0 + r) * C + (c0 + cc)];
  }
  __syncthreads();
  #pragma unroll
  for (int p = 0; p < 16; p++){
    int r = rb + p * 4;
    out[(size_t)(c0 + r) * R + (r0 + cc)] = f2bf(t[cc][r]);
  }
}

__global__ __launch_bounds__(256) void k_prep(
    const float* __restrict__ Wout, const float* __restrict__ Wg, const float* __restrict__ Ug,
    const float* __restrict__ W1, const float* __restrict__ W2, const float* __restrict__ enc,
    const float* __restrict__ dec_hidden,
    unsigned short* WoutT, unsigned short* WgT, unsigned short* UgT,
    unsigned short* W1T, unsigned short* W2T, unsigned short* enc_bf,
    float* h0, unsigned short* h_bf)
{
  __shared__ float tls[64][65];
  int b = blockIdx.x;
  if (b < 4000){ transpose_bf16(Wout, WoutT, 512, 32000, b, tls); return; }
  b -= 4000;
  if (b < 288){ transpose_bf16(Wg, WgT, 768, 1536, b, tls); return; }
  b -= 288;
  if (b < 192){ transpose_bf16(Ug, UgT, 512, 1536, b, tls); return; }
  b -= 192;
  if (b < 64){ transpose_bf16(W1, W1T, 512, 512, b, tls); return; }
  b -= 64;
  if (b < 64){ transpose_bf16(W2, W2T, 512, 512, b, tls); return; }
  b -= 64;
  if (b < 3200){
    size_t i0 = (size_t)b * 2048 + threadIdx.x;
    #pragma unroll
    for (int p = 0; p < 8; p++){ size_t i = i0 + p * 256; enc_bf[i] = f2bf(enc[i]); }
    return;
  }
  b -= 3200;
  { // 8 blocks: h0 = dec_hidden (f32 + bf16 copies)
    size_t i0 = (size_t)b * 2048 + threadIdx.x;
    #pragma unroll
    for (int p = 0; p < 8; p++){
      size_t i = i0 + p * 256; float v = dec_hidden[i];
      h0[i] = v; h_bf[i] = f2bf(v);
    }
  }
}

// ---------------- P1: enc_feat = enc_output @ W2 + b2   (bf16 MFMA) ----------------
__global__ __launch_bounds__(256) void k_encfeat(
    const unsigned short* __restrict__ enc_bf, const unsigned short* __restrict__ W2T,
    const float* __restrict__ b2, unsigned short* __restrict__ ef_bf)
{
  int blk = blockIdx.x;            // 200 x 8
  int bm = blk >> 3, bn = blk & 7;
  int lane = threadIdx.x & 63, w = threadIdx.x >> 6;
  int l15 = lane & 15, quad = lane >> 4;
  int m0 = bm * 64 + w * 16;
  int n0 = bn * 64;
  const unsigned short* arow = enc_bf + (size_t)(m0 + l15) * 512 + quad * 8;
  f32x4 acc[4];
  #pragma unroll
  for (int i = 0; i < 4; i++) acc[i] = (f32x4)0.0f;
  for (int k0 = 0; k0 < 512; k0 += 32){
    bf16x8 a = *(const bf16x8*)(arow + k0);
    #pragma unroll
    for (int nt = 0; nt < 4; nt++){
      const unsigned short* brow = W2T + (size_t)(n0 + nt * 16 + l15) * 512 + k0 + quad * 8;
      acc[nt] = __builtin_amdgcn_mfma_f32_16x16x32_bf16(a, *(const bf16x8*)brow, acc[nt], 0, 0, 0);
    }
  }
  #pragma unroll
  for (int nt = 0; nt < 4; nt++){
    int col = n0 + nt * 16 + l15;
    float bias = b2[col];
    #pragma unroll
    for (int r = 0; r < 4; r++){
      int row = m0 + quad * 4 + r;
      ef_bf[(size_t)row * 512 + col] = f2bf(acc[nt][r] + bias);
    }
  }
}

// ---------------- GRU step (bf16 MFMA, fp32 state) ----------------
__global__ __launch_bounds__(256) void k_gru(
    const int* __restrict__ dec_inp, int t, const float* __restrict__ embedding,
    const float* __restrict__ ctx_old, const float* __restrict__ h_old,
    const unsigned short* __restrict__ WgT, const unsigned short* __restrict__ UgT,
    const float* __restrict__ bg,
    float* __restrict__ h_new, unsigned short* __restrict__ h_new_bf, float* hf_out)
{
  __shared__ unsigned short xs[32 * 776]; // x staging (stride 776), reused for h (stride 520)
  int tid = threadIdx.x;
  for (int i = tid; i < 32 * 768; i += 256){
    int bb = i / 768, c = i - bb * 768;
    float v;
    if (c < 256){ int tok = dec_inp[bb * 41 + t]; v = embedding[(size_t)tok * 256 + c]; }
    else v = ctx_old[bb * 512 + (c - 256)];
    xs[bb * 776 + c] = f2bf(v);
  }
  __syncthreads();
  int lane = tid & 63, w = tid >> 6;
  int l15 = lane & 15, quad = lane >> 4;
  int mt = (w & 1) * 16;
  int n0 = blockIdx.x * 64 + (w >> 1) * 32;
  f32x4 accZ[2], accR[2], accHX[2], accHU[2];
  #pragma unroll
  for (int s = 0; s < 2; s++){ accZ[s] = (f32x4)0.0f; accR[s] = (f32x4)0.0f; accHX[s] = (f32x4)0.0f; accHU[s] = (f32x4)0.0f; }
  // phase 1: x @ Wg (K = 768)
  for (int k0 = 0; k0 < 768; k0 += 32){
    bf16x8 a = *(const bf16x8*)(xs + (mt + l15) * 776 + k0 + quad * 8);
    #pragma unroll
    for (int s = 0; s < 2; s++){
      int col = n0 + s * 16 + l15;
      const unsigned short* bz = WgT + (size_t)col * 768 + k0 + quad * 8;
      const unsigned short* br = WgT + (size_t)(col + 512) * 768 + k0 + quad * 8;
      const unsigned short* bh = WgT + (size_t)(col + 1024) * 768 + k0 + quad * 8;
      accZ[s]  = __builtin_amdgcn_mfma_f32_16x16x32_bf16(a, *(const bf16x8*)bz, accZ[s], 0, 0, 0);
      accR[s]  = __builtin_amdgcn_mfma_f32_16x16x32_bf16(a, *(const bf16x8*)br, accR[s], 0, 0, 0);
      accHX[s] = __builtin_amdgcn_mfma_f32_16x16x32_bf16(a, *(const bf16x8*)bh, accHX[s], 0, 0, 0);
    }
  }
  __syncthreads();
  for (int i = tid; i < 32 * 512; i += 256){
    int bb = i >> 9, c = i & 511;
    xs[bb * 520 + c] = f2bf(h_old[i]);
  }
  __syncthreads();
  // phase 2: h @ Ug (K = 512)
  for (int k0 = 0; k0 < 512; k0 += 32){
    bf16x8 a = *(const bf16x8*)(xs + (mt + l15) * 520 + k0 + quad * 8);
    #pragma unroll
    for (int s = 0; s < 2; s++){
      int col = n0 + s * 16 + l15;
      const unsigned short* bz = UgT + (size_t)col * 512 + k0 + quad * 8;
      const unsigned short* br = UgT + (size_t)(col + 512) * 512 + k0 + quad * 8;
      const unsigned short* bh = UgT + (size_t)(col + 1024) * 512 + k0 + quad * 8;
      accZ[s]  = __builtin_amdgcn_mfma_f32_16x16x32_bf16(a, *(const bf16x8*)bz, accZ[s], 0, 0, 0);
      accR[s]  = __builtin_amdgcn_mfma_f32_16x16x32_bf16(a, *(const bf16x8*)br, accR[s], 0, 0, 0);
      accHU[s] = __builtin_amdgcn_mfma_f32_16x16x32_bf16(a, *(const bf16x8*)bh, accHU[s], 0, 0, 0);
    }
  }
  #pragma unroll
  for (int s = 0; s < 2; s++){
    int col = n0 + s * 16 + l15;
    float bz = bg[col], br = bg[col + 512], bh = bg[col + 1024];
    #pragma unroll
    for (int r = 0; r < 4; r++){
      int bb = mt + quad * 4 + r;
      float z  = fast_sigmoid(accZ[s][r] + bz);
      float rr = fast_sigmoid(accR[s][r] + br);
      float hh = fast_tanh(accHX[s][r] + bh + rr * accHU[s][r]);
      float ho = h_old[bb * 512 + col];
      float hn = z * ho + (1.f - z) * hh;
      h_new[bb * 512 + col] = hn;
      h_new_bf[bb * 512 + col] = f2bf(hn);
      if (hf_out) hf_out[bb * 512 + col] = hn;
    }
  }
}

// ---------------- logits = h@Wout + bout  and  w1h = h@W1 + b1  (fused grid) ----------------
__global__ __launch_bounds__(256) void k_gemm_h(
    const unsigned short* __restrict__ h_bf,
    const unsigned short* __restrict__ WoutT, const float* __restrict__ bout, float* __restrict__ logits,
    const unsigned short* __restrict__ W1T, const float* __restrict__ b1, float* __restrict__ w1h,
    int nb_log)
{
  __shared__ unsigned short hs[32 * 520];
  int tid = threadIdx.x;
  for (int i = tid; i < 8192; i += 256){
    int bb = i >> 8;
    int cp = (i & 255) * 2;
    *(unsigned int*)(hs + bb * 520 + cp) = *(const unsigned int*)(h_bf + bb * 512 + cp);
  }
  __syncthreads();
  int blk = blockIdx.x;
  const unsigned short* Bm; const float* bias; float* out; int n0, ldo;
  if (blk < nb_log){ Bm = WoutT; bias = bout; out = logits; n0 = blk * 64; ldo = VV; }
  else { Bm = W1T; bias = b1; out = w1h; n0 = (blk - nb_log) * 64; ldo = 512; }
  int lane = tid & 63, w = tid >> 6;
  int l15 = lane & 15, quad = lane >> 4;
  int mt = (w & 1) * 16;
  int nbase = n0 + (w >> 1) * 32;
  f32x4 acc[2];
  acc[0] = (f32x4)0.0f; acc[1] = (f32x4)0.0f;
  const unsigned short* arow = hs + (mt + l15) * 520 + quad * 8;
  for (int k0 = 0; k0 < 512; k0 += 32){
    bf16x8 a = *(const bf16x8*)(arow + k0);
    #pragma unroll
    for (int s = 0; s < 2; s++){
      const unsigned short* br = Bm + (size_t)(nbase + s * 16 + l15) * 512 + k0 + quad * 8;
      acc[s] = __builtin_amdgcn_mfma_f32_16x16x32_bf16(a, *(const bf16x8*)br, acc[s], 0, 0, 0);
    }
  }
  #pragma unroll
  for (int s = 0; s < 2; s++){
    int col = nbase + s * 16 + l15;
    float bi = bias[col];
    #pragma unroll
    for (int r = 0; r < 4; r++){
      int row = mt + quad * 4 + r;
      out[(size_t)row * ldo + col] = acc[s][r] + bi;
    }
  }
}

// -------- scores + vocab-softmax partials + pgen h/x partial + (scatter for prev step) --------
__global__ __launch_bounds__(256) void k_score(
    const unsigned short* __restrict__ ef_bf, const float* __restrict__ w1h,
    const float* __restrict__ Wc, const float* __restrict__ Va, const float* __restrict__ bv,
    const float* __restrict__ cov, float* __restrict__ scores,
    const float* __restrict__ logits, float* __restrict__ part,
    const float* __restrict__ h_new, const float* __restrict__ ctx_old,
    const float* __restrict__ embedding, const int* __restrict__ dec_inp, int t,
    const float* __restrict__ Wp, const float* __restrict__ bp, float* __restrict__ pgen_hx,
    const float* __restrict__ attn_prev, const float* __restrict__ pgens_prev,
    const int* __restrict__ eidx, float* __restrict__ final_prev)
{
  int blk = blockIdx.x;
  int tid = threadIdx.x;
  if (blk < 800){ // scores: 32 b x 25 l-tiles of 16
    __shared__ float whs[512], wcs[512], vas[512];
    int b = blk / 25, lt = blk - b * 25;
    for (int i = tid; i < 512; i += 256){ whs[i] = w1h[b * 512 + i]; wcs[i] = Wc[i]; vas[i] = Va[i]; }
    __syncthreads();
    int li = tid >> 4;
    int a0 = (tid & 15) * 32;
    int l = lt * 16 + li;
    float covl = cov ? cov[b * 400 + l] : 0.f;
    const unsigned short* ef = ef_bf + (size_t)(b * 400 + l) * 512 + a0;
    float p = 0.f;
    #pragma unroll
    for (int i = 0; i < 32; i += 8){
      bf16x8 v8 = *(const bf16x8*)(ef + i);
      #pragma unroll
      for (int j = 0; j < 8; j++){
        int aa = a0 + i + j;
        float arg = whs[aa] + bf2f((unsigned short)v8[j]) + covl * wcs[aa];
        p += fast_tanh(arg) * vas[aa];
      }
    }
    p += __shfl_xor(p, 1); p += __shfl_xor(p, 2); p += __shfl_xor(p, 4); p += __shfl_xor(p, 8);
    if ((tid & 15) == 0) scores[b * 400 + l] = p + bv[0];
    return;
  }
  blk -= 800;
  if (blk < 256){ // vocab softmax partials: 32 b x 8 parts of 4000
    int b = blk >> 3, p8 = blk & 7;
    const float* lp = logits + (size_t)b * VV + p8 * 4000;
    __shared__ float red[256];
    float mx = -1e30f;
    for (int i = tid; i < 4000; i += 256) mx = fmaxf(mx, lp[i]);
    red[tid] = mx; __syncthreads();
    for (int s = 128; s > 0; s >>= 1){ if (tid < s) red[tid] = fmaxf(red[tid], red[tid + s]); __syncthreads(); }
    mx = red[0]; __syncthreads();
    float sm = 0.f;
    for (int i = tid; i < 4000; i += 256) sm += __expf(lp[i] - mx);
    red[tid] = sm; __syncthreads();
    for (int s = 128; s > 0; s >>= 1){ if (tid < s) red[tid] += red[tid + s]; __syncthreads(); }
    if (tid == 0){ part[(b * 8 + p8) * 2] = mx; part[(b * 8 + p8) * 2 + 1] = red[0]; }
    return;
  }
  blk -= 256;
  if (blk < 32){ // pgen partial (h_new, emb_t, ctx_old parts): one block per b
    int b = blk;
    __shared__ float red[256];
    float p = 0.f;
    for (int i = tid; i < 1280; i += 256){
      float xv, wv;
      if (i < 512){ xv = h_new[b * 512 + i]; wv = Wp[512 + i]; }
      else if (i < 768){ int e = i - 512; int tok = dec_inp[b * 41 + t]; xv = embedding[(size_t)tok * 256 + e]; wv = Wp[1024 + e]; }
      else { int c = i - 768; xv = ctx_old[b * 512 + c]; wv = Wp[1280 + c]; }
      p += xv * wv;
    }
    red[tid] = p; __syncthreads();
    for (int s = 128; s > 0; s >>= 1){ if (tid < s) red[tid] += red[tid + s]; __syncthreads(); }
    if (tid == 0) pgen_hx[b] = red[0] + bp[0];
    return;
  }
  blk -= 32;
  { // scatter-add copy dist for PREVIOUS step (base final already written by k_final)
    if (!final_prev) return;
    int i = blk * 256 + tid;
    if (i >= 12800) return;
    int b = i / 400;
    float wv = (1.f - pgens_prev[b]) * attn_prev[i];
    atomicAdd(final_prev + (size_t)b * VEXT + eidx[i], wv);
  }
}

// ---------------- attention finalize: softmax over L, mask, renorm, cov update ----------------
__global__ __launch_bounds__(256) void k_attn_fin(
    const float* __restrict__ scores, const float* __restrict__ mask,
    const float* __restrict__ cov_in, float* __restrict__ attn_cur,
    float* attn_out, float* cov_out,
    const float* __restrict__ part, float* __restrict__ rowMS, int do_ms)
{
  int b = blockIdx.x, tid = threadIdx.x;
  __shared__ float sc[400];
  __shared__ float red[256];
  float mx = -1e30f;
  for (int i = tid; i < 400; i += 256){ float s = scores[b * 400 + i]; sc[i] = s; mx = fmaxf(mx, s); }
  red[tid] = mx; __syncthreads();
  for (int s = 128; s > 0; s >>= 1){ if (tid < s) red[tid] = fmaxf(red[tid], red[tid + s]); __syncthreads(); }
  mx = red[0]; __syncthreads();
  float sm = 0.f;
  for (int i = tid; i < 400; i += 256){ float e = __expf(sc[i] - mx) * mask[b * 400 + i]; sc[i] = e; sm += e; }
  red[tid] = sm; __syncthreads();
  for (int s = 128; s > 0; s >>= 1){ if (tid < s) red[tid] += red[tid + s]; __syncthreads(); }
  float inv = __builtin_amdgcn_rcpf(red[0]);
  __syncthreads();
  for (int i = tid; i < 400; i += 256){
    float a = sc[i] * inv;
    attn_cur[b * 400 + i] = a;
    if (attn_out) attn_out[b * 400 + i] = a;
    float cv = (cov_in ? cov_in[b * 400 + i] : 0.f) + a;
    if (cov_out) cov_out[b * 400 + i] = cv;
  }
  if (do_ms && tid == 0){
    float M = -1e30f;
    for (int p = 0; p < 8; p++) M = fmaxf(M, part[(b * 8 + p) * 2]);
    float S = 0.f;
    for (int p = 0; p < 8; p++) S += part[(b * 8 + p) * 2 + 1] * __expf(part[(b * 8 + p) * 2] - M);
    rowMS[b * 2] = M; rowMS[b * 2 + 1] = S;
  }
}

// ---------------- context = attn^T · enc_output ----------------
__global__ __launch_bounds__(256) void k_context(
    const float* __restrict__ attn_cur, const unsigned short* __restrict__ enc_bf,
    float* __restrict__ ctx_out, float* ctxf_out)
{
  int blk = blockIdx.x; // 32 b x 8 col-tiles of 64
  int b = blk >> 3, ct = blk & 7;
  int tid = threadIdx.x;
  __shared__ float at[400];
  __shared__ float red[8][64];
  for (int i = tid; i < 400; i += 256) at[i] = attn_cur[b * 400 + i];
  __syncthreads();
  int colp = (tid & 31) * 2;
  int chunk = tid >> 5;
  const unsigned short* base = enc_bf + (size_t)b * 400 * 512 + ct * 64 + colp;
  float a0 = 0.f, a1 = 0.f;
  for (int i = 0; i < 50; i++){
    int l = chunk * 50 + i;
    unsigned int u = *(const unsigned int*)(base + (size_t)l * 512);
    float av = at[l];
    a0 += av * bf2f((unsigned short)(u & 0xffffu));
    a1 += av * bf2f((unsigned short)(u >> 16));
  }
  red[chunk][colp] = a0; red[chunk][colp + 1] = a1;
  __syncthreads();
  if (tid < 64){
    float s = 0.f;
    #pragma unroll
    for (int c = 0; c < 8; c++) s += red[c][tid];
    int col = ct * 64 + tid;
    ctx_out[b * 512 + col] = s;
    if (ctxf_out) ctxf_out[b * 512 + col] = s;
  }
}

// ---------------- final dist vocab part + pgen ----------------
__global__ __launch_bounds__(256) void k_final(
    const float* __restrict__ logits, const float* __restrict__ rowMS,
    const float* __restrict__ ctx_new, const float* __restrict__ Wp,
    const float* __restrict__ pgen_hx, float* __restrict__ final_t, float* __restrict__ pgens_t)
{
  int blk = blockIdx.x; // 32 b x 32 v-tiles of 1024
  int b = blk >> 5, vt = blk & 31;
  int tid = threadIdx.x;
  __shared__ float s_pg;
  if (tid < 64){
    float p = 0.f;
    for (int i = tid; i < 512; i += 64) p += ctx_new[b * 512 + i] * Wp[i];
    p += __shfl_down(p, 32); p += __shfl_down(p, 16); p += __shfl_down(p, 8);
    p += __shfl_down(p, 4); p += __shfl_down(p, 2); p += __shfl_down(p, 1);
    if (tid == 0){
      float pg = fast_sigmoid(p + pgen_hx[b]);
      s_pg = pg;
      if (vt == 0) pgens_t[b] = pg;
    }
  }
  __syncthreads();
  float pg = s_pg;
  float M = rowMS[b * 2], Sinv = __builtin_amdgcn_rcpf(rowMS[b * 2 + 1]);
  int v0 = vt * 1024 + tid * 4;
  float val[4];
  if (v0 + 3 < VV){
    f32x4 lg = *(const f32x4*)(logits + (size_t)b * VV + v0);
    #pragma unroll
    for (int j = 0; j < 4; j++) val[j] = pg * __expf(lg[j] - M) * Sinv;
  } else {
    #pragma unroll
    for (int j = 0; j < 4; j++){
      int v = v0 + j;
      val[j] = (v < VV) ? pg * __expf(logits[(size_t)b * VV + v] - M) * Sinv : 0.f;
    }
  }
  #pragma unroll
  for (int j = 0; j < 4; j++){
    int v = v0 + j;
    if (v < VEXT) final_t[(size_t)b * VEXT + v] = val[j];
  }
}

// ---------------- trailing scatter for the last step ----------------
__global__ __launch_bounds__(256) void k_scatter(
    const int* __restrict__ eidx, const float* __restrict__ attn_prev,
    const float* __restrict__ pgens_prev, float* __restrict__ final_prev)
{
  int i = blockIdx.x * 256 + threadIdx.x;
  if (i >= 12800) return;
  int b = i / 400;
  float wv = (1.f - pgens_prev[b]) * attn_prev[i];
  atomicAdd(final_prev + (size_t)b * VEXT + eidx[i], wv);
}

extern "C" void kernel_launch(void* const* d_in, const int* in_sizes, int n_in,
                              void* d_out, int out_size, void* d_ws, size_t ws_size,
                              hipStream_t stream) {
  const int*   dec_inp    = (const int*)d_in[0];
  const int*   eidx       = (const int*)d_in[1];
  const float* mask       = (const float*)d_in[2];
  const float* enc        = (const float*)d_in[4];
  const float* dec_hidden = (const float*)d_in[5];
  const float* embedding  = (const float*)d_in[6];
  const float* W1  = (const float*)d_in[7];
  const float* b1  = (const float*)d_in[8];
  const float* W2  = (const float*)d_in[9];
  const float* b2  = (const float*)d_in[10];
  const float* Wc  = (const float*)d_in[11];
  const float* Va  = (const float*)d_in[12];
  const float* bv  = (const float*)d_in[13];
  const float* Wg  = (const float*)d_in[14];
  const float* Ug  = (const float*)d_in[15];
  const float* bg  = (const float*)d_in[16];
  const float* Wout = (const float*)d_in[17];
  const float* bout = (const float*)d_in[18];
  const float* Wp  = (const float*)d_in[19];
  const float* bp  = (const float*)d_in[20];

  float* out    = (float*)d_out;
  float* final_ = out;                               // 40*32*32050
  float* attns  = out + (size_t)40 * 32 * VEXT;      // 40*32*400
  float* covs   = attns + 512000;
  float* hf     = covs + 512000;
  float* ctxf   = hf + 16384;
  float* pgens  = ctxf + 16384;

  char* wsb = (char*)d_ws; size_t off = 0;
  auto A = [&](size_t bytes)->char*{ char* p = wsb + off; off += (bytes + 255) & ~(size_t)255; return p; };
  float* logits   = (float*)A((size_t)32 * VV * 4);
  float* hbuf0    = (float*)A(65536);
  float* hbuf1    = (float*)A(65536);
  float* ctxbuf0  = (float*)A(65536);
  float* ctxbuf1  = (float*)A(65536);
  float* w1h      = (float*)A(65536);
  float* scores   = (float*)A(51200);
  float* attn_cur = (float*)A(51200);
  float* part     = (float*)A(2048);
  float* rowMS    = (float*)A(256);
  float* pgen_hx  = (float*)A(128);
  unsigned short* h_bf   = (unsigned short*)A(32768);
  unsigned short* enc_bf = (unsigned short*)A((size_t)32 * 400 * 512 * 2);
  unsigned short* ef_bf  = (unsigned short*)A((size_t)32 * 400 * 512 * 2);
  unsigned short* W2T    = (unsigned short*)A(524288);
  unsigned short* W1T    = (unsigned short*)A(524288);
  unsigned short* WgT    = (unsigned short*)A(2359296);
  unsigned short* UgT    = (unsigned short*)A(1572864);
  unsigned short* WoutT  = (unsigned short*)A((size_t)VV * 512 * 2);
  float* hbuf[2]   = {hbuf0, hbuf1};
  float* ctxbuf[2] = {ctxbuf0, ctxbuf1};

  // ---- prologue ----
  k_prep<<<7816, 256, 0, stream>>>(Wout, Wg, Ug, W1, W2, enc, dec_hidden,
                                   WoutT, WgT, UgT, W1T, W2T, enc_bf, hbuf[0], h_bf);
  k_encfeat<<<1600, 256, 0, stream>>>(enc_bf, W2T, b2, ef_bf);
  k_gemm_h<<<8, 256, 0, stream>>>(h_bf, WoutT, bout, logits, W1T, b1, w1h, 0); // w1h only
  k_score<<<800, 256, 0, stream>>>(ef_bf, w1h, Wc, Va, bv, nullptr, scores,
                                   logits, part, hbuf[1], ctxbuf[0], embedding, dec_inp, 0,
                                   Wp, bp, pgen_hx, nullptr, nullptr, eidx, nullptr);
  k_attn_fin<<<32, 256, 0, stream>>>(scores, mask, nullptr, attn_cur,
                                     attns, covs, part, rowMS, 0);
  k_context<<<256, 256, 0, stream>>>(attn_cur, enc_bf, ctxbuf[0], nullptr);

  // ---- decode loop ----
  for (int t = 0; t < 40; t++){
    int p = t & 1;
    k_gru<<<8, 256, 0, stream>>>(dec_inp, t, embedding, ctxbuf[p], hbuf[p],
                                 WgT, UgT, bg, hbuf[p ^ 1], h_bf, (t == 39) ? hf : nullptr);
    k_gemm_h<<<508, 256, 0, stream>>>(h_bf, WoutT, bout, logits, W1T, b1, w1h, 500);
    k_score<<<(t >= 1 ? 1138 : 1088), 256, 0, stream>>>(
        ef_bf, w1h, Wc, Va, bv, covs + (size_t)t * 12800, scores,
        logits, part, hbuf[p ^ 1], ctxbuf[p], embedding, dec_inp, t,
        Wp, bp, pgen_hx,
        (t >= 1) ? attns + (size_t)(t - 1) * 12800 : nullptr,
        (t >= 1) ? pgens + (t - 1) * 32 : nullptr,
        eidx,
        (t >= 1) ? final_ + (size_t)(t - 1) * 32 * VEXT : nullptr);
    k_attn_fin<<<32, 256, 0, stream>>>(scores, mask, covs + (size_t)t * 12800, attn_cur,
                                       (t < 39) ? attns + (size_t)(t + 1) * 12800 : nullptr,
                                       (t < 39) ? covs + (size_t)(t + 1) * 12800 : nullptr,
                                       part, rowMS, 1);
    k_context<<<256, 256, 0, stream>>>(attn_cur, enc_bf, ctxbuf[p ^ 1], (t == 39) ? ctxf : nullptr);
    k_final<<<1024, 256, 0, stream>>>(logits, rowMS, ctxbuf[p ^ 1], Wp, pgen_hx,
                                      final_ + (size_t)t * 32 * VEXT, pgens + t * 32);
  }
  k_scatter<<<50, 256, 0, stream>>>(eidx, attns + (size_t)39 * 12800, pgens + 39 * 32,
                                    final_ + (size_t)39 * 32 * VEXT);
}

// Round 2
// 3419.173 us; speedup vs baseline: 1.3632x; 1.3632x over previous
//
#include <hip/hip_runtime.h>
#include <hip/hip_bf16.h>

// PGN decoder: B=32, L=400, T=40 steps, H=A=512, E=256, V=32000, oov=50.
// Outputs (flat in d_out, fp32): final (40,32,32050) | attns (40,32,400) |
// covs (40,32,400) | h_f (32,512) | ctx_f (32,512) | pgens (40,32)
#define BB 32
#define LL 400
#define TT 40
#define HH 512
#define VV 32000
#define VEXT 32050

typedef __attribute__((ext_vector_type(8))) short bf16x8;
typedef __attribute__((ext_vector_type(4))) float f32x4;
typedef __attribute__((ext_vector_type(2))) float f32x2;

__device__ __forceinline__ float bf2f(unsigned short u){
  union { unsigned int i; float f; } v; v.i = ((unsigned int)u) << 16; return v.f;
}
__device__ __forceinline__ unsigned short f2bf(float f){
  union { float f; unsigned int i; } v; v.f = f;
  unsigned int i = v.i;
  return (unsigned short)((i + 0x7FFFu + ((i >> 16) & 1u)) >> 16); // RNE
}
__device__ __forceinline__ float fast_tanh(float x){
  x = fminf(20.f, fmaxf(-20.f, x));
  float e = __expf(2.f * x);
  return (e - 1.f) * __builtin_amdgcn_rcpf(e + 1.f);
}
__device__ __forceinline__ float fast_sigmoid(float x){
  x = fminf(30.f, fmaxf(-30.f, x));
  return __builtin_amdgcn_rcpf(1.f + __expf(-x));
}

// ---------------- P0: weight transposes (f32 -> bf16 NxK) + converts + pgen_emb ----------------
__device__ void transpose_bf16(const float* __restrict__ in, unsigned short* __restrict__ out,
                               int R, int C, int tile, float (*t)[65]){
  int tcn = C >> 6;
  int tr = tile / tcn, tc = tile - tr * tcn;
  int r0 = tr << 6, c0 = tc << 6;
  int cc = threadIdx.x & 63, rb = threadIdx.x >> 6;
  #pragma unroll
  for (int p = 0; p < 16; p++){
    int r = rb + p * 4;
    t[r][cc] = in[(size_t)(r0 + r) * C + (c0 + cc)];
  }
  __syncthreads();
  #pragma unroll
  for (int p = 0; p < 16; p++){
    int r = rb + p * 4;
    out[(size_t)(c0 + r) * R + (r0 + cc)] = f2bf(t[cc][r]);
  }
}

__global__ __launch_bounds__(256) void k_prep(
    const float* __restrict__ Wout, const float* __restrict__ Wg, const float* __restrict__ Ug,
    const float* __restrict__ W1, const float* __restrict__ W2, const float* __restrict__ enc,
    const float* __restrict__ dec_hidden, const int* __restrict__ dec_inp,
    const float* __restrict__ embedding, const float* __restrict__ Wp,
    unsigned short* WoutT, unsigned short* WgT, unsigned short* UgT,
    unsigned short* W1T, unsigned short* W2T, unsigned short* enc_bf,
    float* h0, unsigned short* h_bf, float* pgen_emb)
{
  __shared__ float tls[64][65];
  int b = blockIdx.x;
  int tid = threadIdx.x;
  if (b < 4000){ transpose_bf16(Wout, WoutT, 512, 32000, b, tls); return; }
  b -= 4000;
  if (b < 288){ transpose_bf16(Wg, WgT, 768, 1536, b, tls); return; }
  b -= 288;
  if (b < 192){ transpose_bf16(Ug, UgT, 512, 1536, b, tls); return; }
  b -= 192;
  if (b < 64){ transpose_bf16(W1, W1T, 512, 512, b, tls); return; }
  b -= 64;
  if (b < 64){ transpose_bf16(W2, W2T, 512, 512, b, tls); return; }
  b -= 64;
  if (b < 3200){
    size_t i0 = (size_t)b * 2048 + tid;
    #pragma unroll
    for (int p = 0; p < 8; p++){ size_t i = i0 + p * 256; enc_bf[i] = f2bf(enc[i]); }
    return;
  }
  b -= 3200;
  if (b < 8){ // h0 = dec_hidden (f32 + bf16 copies)
    size_t i0 = (size_t)b * 2048 + tid;
    #pragma unroll
    for (int p = 0; p < 8; p++){
      size_t i = i0 + p * 256; float v = dec_hidden[i];
      h0[i] = v; h_bf[i] = f2bf(v);
    }
    return;
  }
  b -= 8;
  { // 40 blocks: pgen_emb[t][b] = emb(t,b) . Wp[1024:1280]
    int t = b;
    int bb = tid >> 3, l8 = tid & 7;
    int tok = dec_inp[bb * 41 + t];
    const float* e = embedding + (size_t)tok * 256 + l8 * 32;
    const float* wp = Wp + 1024 + l8 * 32;
    float p = 0.f;
    #pragma unroll
    for (int j = 0; j < 32; j++) p += e[j] * wp[j];
    p += __shfl_xor(p, 1); p += __shfl_xor(p, 2); p += __shfl_xor(p, 4);
    if (l8 == 0) pgen_emb[t * 32 + bb] = p;
  }
}

// ---------------- P1: embW[t,b,:] = emb(t,b) @ Wg[0:256,:] + bg   (all steps) ----------------
__global__ __launch_bounds__(256) void k_embw(
    const int* __restrict__ dec_inp, const float* __restrict__ embedding,
    const unsigned short* __restrict__ WgT, const float* __restrict__ bg,
    float* __restrict__ embW)
{
  __shared__ unsigned short as[64 * 264];
  int blk = blockIdx.x;         // 20 m-tiles x 24 n-tiles
  int bm = blk / 24, bn = blk - bm * 24;
  int m0 = bm * 64, n0 = bn * 64;
  int tid = threadIdx.x;
  for (int i = tid; i < 64 * 256; i += 256){
    int r = i >> 8, c = i & 255;
    int R = m0 + r; int t = R >> 5, bb = R & 31;
    int tok = dec_inp[bb * 41 + t];
    as[r * 264 + c] = f2bf(embedding[(size_t)tok * 256 + c]);
  }
  __syncthreads();
  int lane = tid & 63, w = tid >> 6;
  int l15 = lane & 15, quad = lane >> 4;
  const unsigned short* arow = as + (w * 16 + l15) * 264 + quad * 8;
  f32x4 acc[4];
  #pragma unroll
  for (int i = 0; i < 4; i++) acc[i] = (f32x4)0.0f;
  for (int k0 = 0; k0 < 256; k0 += 32){
    bf16x8 a = *(const bf16x8*)(arow + k0);
    #pragma unroll
    for (int nt = 0; nt < 4; nt++){
      const unsigned short* brow = WgT + (size_t)(n0 + nt * 16 + l15) * 768 + k0 + quad * 8;
      acc[nt] = __builtin_amdgcn_mfma_f32_16x16x32_bf16(a, *(const bf16x8*)brow, acc[nt], 0, 0, 0);
    }
  }
  #pragma unroll
  for (int nt = 0; nt < 4; nt++){
    int col = n0 + nt * 16 + l15;
    float bias = bg[col];
    #pragma unroll
    for (int r = 0; r < 4; r++){
      int row = m0 + w * 16 + quad * 4 + r;
      embW[(size_t)row * 1536 + col] = acc[nt][r] + bias;
    }
  }
}

// ---------------- P2: enc_feat = enc_output @ W2 + b2   (bf16 MFMA) ----------------
__global__ __launch_bounds__(256) void k_encfeat(
    const unsigned short* __restrict__ enc_bf, const unsigned short* __restrict__ W2T,
    const float* __restrict__ b2, unsigned short* __restrict__ ef_bf)
{
  int blk = blockIdx.x;            // 200 x 8
  int bm = blk >> 3, bn = blk & 7;
  int lane = threadIdx.x & 63, w = threadIdx.x >> 6;
  int l15 = lane & 15, quad = lane >> 4;
  int m0 = bm * 64 + w * 16;
  int n0 = bn * 64;
  const unsigned short* arow = enc_bf + (size_t)(m0 + l15) * 512 + quad * 8;
  f32x4 acc[4];
  #pragma unroll
  for (int i = 0; i < 4; i++) acc[i] = (f32x4)0.0f;
  for (int k0 = 0; k0 < 512; k0 += 32){
    bf16x8 a = *(const bf16x8*)(arow + k0);
    #pragma unroll
    for (int nt = 0; nt < 4; nt++){
      const unsigned short* brow = W2T + (size_t)(n0 + nt * 16 + l15) * 512 + k0 + quad * 8;
      acc[nt] = __builtin_amdgcn_mfma_f32_16x16x32_bf16(a, *(const bf16x8*)brow, acc[nt], 0, 0, 0);
    }
  }
  #pragma unroll
  for (int nt = 0; nt < 4; nt++){
    int col = n0 + nt * 16 + l15;
    float bias = b2[col];
    #pragma unroll
    for (int r = 0; r < 4; r++){
      int row = m0 + quad * 4 + r;
      ef_bf[(size_t)row * 512 + col] = f2bf(acc[nt][r] + bias);
    }
  }
}

// ---------------- final-dist writer (shared by k_gru-hosted blocks and k_fin) ----------------
__device__ void final_dist_write(int f, int tid,
    const float* __restrict__ logits, const float* __restrict__ rowMS,
    const float* __restrict__ pgen_hd, const float* __restrict__ pgen_cn,
    const float* __restrict__ pgen_co, const float* __restrict__ pgen_emb_t,
    const float* __restrict__ bp, float* __restrict__ final_t, float* __restrict__ pgens_t)
{
  __shared__ float s_pg;
  int b = f >> 4, vt = f & 15;
  if (tid == 0){
    float p = pgen_hd[b] + pgen_emb_t[b] + bp[0];
    #pragma unroll
    for (int j = 0; j < 8; j++) p += pgen_cn[b * 8 + j] + pgen_co[b * 8 + j];
    float pg = fast_sigmoid(p);
    s_pg = pg;
    if (vt == 0) pgens_t[b] = pg;
  }
  __syncthreads();
  float pg = s_pg;
  float M = rowMS[b * 2];
  float Sinv = __builtin_amdgcn_rcpf(rowMS[b * 2 + 1]);
  const float* lg = logits + (size_t)b * VV;
  float* dst = final_t + (size_t)b * VEXT;
  int v0 = vt * 2048 + tid * 8;
  if (v0 + 7 < VV){
    f32x4 x0 = *(const f32x4*)(lg + v0);
    f32x4 x1 = *(const f32x4*)(lg + v0 + 4);
    f32x2 y;
    y.x = pg * __expf(x0.x - M) * Sinv; y.y = pg * __expf(x0.y - M) * Sinv;
    __builtin_nontemporal_store(y, (f32x2*)(dst + v0));
    y.x = pg * __expf(x0.z - M) * Sinv; y.y = pg * __expf(x0.w - M) * Sinv;
    __builtin_nontemporal_store(y, (f32x2*)(dst + v0 + 2));
    y.x = pg * __expf(x1.x - M) * Sinv; y.y = pg * __expf(x1.y - M) * Sinv;
    __builtin_nontemporal_store(y, (f32x2*)(dst + v0 + 4));
    y.x = pg * __expf(x1.z - M) * Sinv; y.y = pg * __expf(x1.w - M) * Sinv;
    __builtin_nontemporal_store(y, (f32x2*)(dst + v0 + 6));
  } else {
    #pragma unroll
    for (int j = 0; j < 8; j++){
      int v = v0 + j;
      float val = (v < VV) ? pg * __expf(lg[v] - M) * Sinv : 0.f;
      if (v < VEXT) __builtin_nontemporal_store(val, dst + v);
    }
  }
}

// ---------------- GRU step (bf16 MFMA, fp32 state) + hosted final(t-1) ----------------
__global__ __launch_bounds__(256) void k_gru(
    const float* __restrict__ ctx_old, const float* __restrict__ h_old,
    const float* __restrict__ embW_t,
    const unsigned short* __restrict__ WgT, const unsigned short* __restrict__ UgT,
    float* __restrict__ h_new, unsigned short* __restrict__ h_new_bf, float* hf_out,
    const float* __restrict__ logits, const float* __restrict__ rowMS,
    const float* __restrict__ pgen_hd, const float* __restrict__ pgen_cn,
    const float* __restrict__ pgen_co, const float* __restrict__ pgen_emb_prev,
    const float* __restrict__ bp, float* __restrict__ final_prev, float* __restrict__ pgens_prev)
{
  int blk = blockIdx.x;
  int tid = threadIdx.x;
  if (blk >= 8){
    final_dist_write(blk - 8, tid, logits, rowMS, pgen_hd, pgen_cn, pgen_co,
                     pgen_emb_prev, bp, final_prev, pgens_prev);
    return;
  }
  __shared__ unsigned short xs[32 * 520];
  // stage ctx_old as bf16
  for (int i = tid; i < 32 * 512; i += 256){
    int bb = i >> 9, c = i & 511;
    xs[bb * 520 + c] = f2bf(ctx_old[i]);
  }
  __syncthreads();
  int lane = tid & 63, w = tid >> 6;
  int l15 = lane & 15, quad = lane >> 4;
  int mt = (w & 1) * 16;
  int n0 = blk * 64 + (w >> 1) * 32;
  f32x4 accZ[2], accR[2], accH[2], accU[2];
  #pragma unroll
  for (int s = 0; s < 2; s++){
    int col = n0 + s * 16 + l15;
    #pragma unroll
    for (int r = 0; r < 4; r++){
      int row = mt + quad * 4 + r;
      const float* e = embW_t + (size_t)row * 1536 + col;
      accZ[s][r] = e[0]; accR[s][r] = e[512]; accH[s][r] = e[1024];
      accU[s][r] = 0.f;
    }
  }
  // phase 1: ctx_old @ Wg[256:768,:]  (K = 512)
  for (int k0 = 0; k0 < 512; k0 += 32){
    bf16x8 a = *(const bf16x8*)(xs + (mt + l15) * 520 + k0 + quad * 8);
    #pragma unroll
    for (int s = 0; s < 2; s++){
      int col = n0 + s * 16 + l15;
      const unsigned short* bz = WgT + (size_t)col * 768 + 256 + k0 + quad * 8;
      const unsigned short* br = WgT + (size_t)(col + 512) * 768 + 256 + k0 + quad * 8;
      const unsigned short* bh = WgT + (size_t)(col + 1024) * 768 + 256 + k0 + quad * 8;
      accZ[s] = __builtin_amdgcn_mfma_f32_16x16x32_bf16(a, *(const bf16x8*)bz, accZ[s], 0, 0, 0);
      accR[s] = __builtin_amdgcn_mfma_f32_16x16x32_bf16(a, *(const bf16x8*)br, accR[s], 0, 0, 0);
      accH[s] = __builtin_amdgcn_mfma_f32_16x16x32_bf16(a, *(const bf16x8*)bh, accH[s], 0, 0, 0);
    }
  }
  __syncthreads();
  for (int i = tid; i < 32 * 512; i += 256){
    int bb = i >> 9, c = i & 511;
    xs[bb * 520 + c] = f2bf(h_old[i]);
  }
  __syncthreads();
  // phase 2: h_old @ Ug  (K = 512)
  for (int k0 = 0; k0 < 512; k0 += 32){
    bf16x8 a = *(const bf16x8*)(xs + (mt + l15) * 520 + k0 + quad * 8);
    #pragma unroll
    for (int s = 0; s < 2; s++){
      int col = n0 + s * 16 + l15;
      const unsigned short* bz = UgT + (size_t)col * 512 + k0 + quad * 8;
      const unsigned short* br = UgT + (size_t)(col + 512) * 512 + k0 + quad * 8;
      const unsigned short* bh = UgT + (size_t)(col + 1024) * 512 + k0 + quad * 8;
      accZ[s] = __builtin_amdgcn_mfma_f32_16x16x32_bf16(a, *(const bf16x8*)bz, accZ[s], 0, 0, 0);
      accR[s] = __builtin_amdgcn_mfma_f32_16x16x32_bf16(a, *(const bf16x8*)br, accR[s], 0, 0, 0);
      accU[s] = __builtin_amdgcn_mfma_f32_16x16x32_bf16(a, *(const bf16x8*)bh, accU[s], 0, 0, 0);
    }
  }
  #pragma unroll
  for (int s = 0; s < 2; s++){
    int col = n0 + s * 16 + l15;
    #pragma unroll
    for (int r = 0; r < 4; r++){
      int bb = mt + quad * 4 + r;
      float z  = fast_sigmoid(accZ[s][r]);
      float rr = fast_sigmoid(accR[s][r]);
      float hh = fast_tanh(accH[s][r] + rr * accU[s][r]);
      float ho = h_old[bb * 512 + col];
      float hn = z * ho + (1.f - z) * hh;
      h_new[bb * 512 + col] = hn;
      h_new_bf[bb * 512 + col] = f2bf(hn);
      if (hf_out) hf_out[bb * 512 + col] = hn;
    }
  }
}

// ---- logits = h@Wout + bout (+ per-tile softmax partials), w1h = h@W1 + b1, scatter(t-1) ----
__global__ __launch_bounds__(256) void k_gemm_h(
    const unsigned short* __restrict__ h_bf,
    const unsigned short* __restrict__ WoutT, const float* __restrict__ bout, float* __restrict__ logits,
    const unsigned short* __restrict__ W1T, const float* __restrict__ b1, float* __restrict__ w1h,
    int nb_log, float* __restrict__ tilems,
    const int* __restrict__ eidx, const float* __restrict__ attn_prev,
    const float* __restrict__ pgens_prev, float* __restrict__ final_prev)
{
  int blk = blockIdx.x;
  int tid = threadIdx.x;
  if (blk >= nb_log + 8){ // scatter-add copy dist for PREVIOUS step
    int i = (blk - nb_log - 8) * 256 + tid;
    if (i >= 12800 || !final_prev) return;
    int b = i / 400;
    float wv = (1.f - pgens_prev[b]) * attn_prev[i];
    atomicAdd(final_prev + (size_t)b * VEXT + eidx[i], wv);
    return;
  }
  __shared__ unsigned short hs[32 * 520];
  __shared__ float smp[4][16][2];
  for (int i = tid; i < 8192; i += 256){
    int bb = i >> 8;
    int cp = (i & 255) * 2;
    *(unsigned int*)(hs + bb * 520 + cp) = *(const unsigned int*)(h_bf + bb * 512 + cp);
  }
  __syncthreads();
  int is_logits = (blk < nb_log);
  const unsigned short* Bm; const float* bias; float* out; int n0, ldo;
  if (is_logits){ Bm = WoutT; bias = bout; out = logits; n0 = blk * 64; ldo = VV; }
  else { Bm = W1T; bias = b1; out = w1h; n0 = (blk - nb_log) * 64; ldo = 512; }
  int lane = tid & 63, w = tid >> 6;
  int l15 = lane & 15, quad = lane >> 4;
  int mt = (w & 1) * 16;
  int nbase = n0 + (w >> 1) * 32;
  f32x4 acc[2];
  acc[0] = (f32x4)0.0f; acc[1] = (f32x4)0.0f;
  const unsigned short* arow = hs + (mt + l15) * 520 + quad * 8;
  for (int k0 = 0; k0 < 512; k0 += 32){
    bf16x8 a = *(const bf16x8*)(arow + k0);
    #pragma unroll
    for (int s = 0; s < 2; s++){
      const unsigned short* br = Bm + (size_t)(nbase + s * 16 + l15) * 512 + k0 + quad * 8;
      acc[s] = __builtin_amdgcn_mfma_f32_16x16x32_bf16(a, *(const bf16x8*)br, acc[s], 0, 0, 0);
    }
  }
  float vv[2][4];
  #pragma unroll
  for (int s = 0; s < 2; s++){
    int col = nbase + s * 16 + l15;
    float bi = bias[col];
    #pragma unroll
    for (int r = 0; r < 4; r++){
      int row = mt + quad * 4 + r;
      vv[s][r] = acc[s][r] + bi;
      out[(size_t)row * ldo + col] = vv[s][r];
    }
  }
  if (is_logits){ // per-(b, 64-col-tile) online-softmax partials
    #pragma unroll
    for (int r = 0; r < 4; r++){
      float m = fmaxf(vv[0][r], vv[1][r]);
      m = fmaxf(m, __shfl_xor(m, 1)); m = fmaxf(m, __shfl_xor(m, 2));
      m = fmaxf(m, __shfl_xor(m, 4)); m = fmaxf(m, __shfl_xor(m, 8));
      float e = __expf(vv[0][r] - m) + __expf(vv[1][r] - m);
      e += __shfl_xor(e, 1); e += __shfl_xor(e, 2); e += __shfl_xor(e, 4); e += __shfl_xor(e, 8);
      if (l15 == 0){ smp[w][quad * 4 + r][0] = m; smp[w][quad * 4 + r][1] = e; }
    }
    __syncthreads();
    if (tid < 32){
      int half = tid >> 4, row = tid & 15;
      float ma = smp[half][row][0], mb = smp[half + 2][row][0];
      float M = fmaxf(ma, mb);
      float S = smp[half][row][1] * __expf(ma - M) + smp[half + 2][row][1] * __expf(mb - M);
      tilems[((size_t)blk * 32 + half * 16 + row) * 2] = M;
      tilems[((size_t)blk * 32 + half * 16 + row) * 2 + 1] = S;
    }
  }
}

// -------- attention scores + pgen h-dot --------
__global__ __launch_bounds__(256) void k_score(
    const unsigned short* __restrict__ ef_bf, const float* __restrict__ w1h,
    const float* __restrict__ Wc, const float* __restrict__ Va, const float* __restrict__ bv,
    const float* __restrict__ cov, float* __restrict__ scores,
    const float* __restrict__ h_new, const float* __restrict__ Wp,
    float* __restrict__ pgen_hd)
{
  int blk = blockIdx.x;
  int tid = threadIdx.x;
  if (blk < 800){ // scores: 32 b x 25 l-tiles of 16
    __shared__ float whs[512], wcs[512], vas[512];
    int b = blk / 25, lt = blk - b * 25;
    for (int i = tid; i < 512; i += 256){ whs[i] = w1h[b * 512 + i]; wcs[i] = Wc[i]; vas[i] = Va[i]; }
    __syncthreads();
    int li = tid >> 4;
    int a0 = (tid & 15) * 32;
    int l = lt * 16 + li;
    float covl = cov ? cov[b * 400 + l] : 0.f;
    const unsigned short* ef = ef_bf + (size_t)(b * 400 + l) * 512 + a0;
    float p = 0.f;
    #pragma unroll
    for (int i = 0; i < 32; i += 8){
      bf16x8 v8 = *(const bf16x8*)(ef + i);
      #pragma unroll
      for (int j = 0; j < 8; j++){
        int aa = a0 + i + j;
        float arg = whs[aa] + bf2f((unsigned short)v8[j]) + covl * wcs[aa];
        p += fast_tanh(arg) * vas[aa];
      }
    }
    p += __shfl_xor(p, 1); p += __shfl_xor(p, 2); p += __shfl_xor(p, 4); p += __shfl_xor(p, 8);
    if ((tid & 15) == 0) scores[b * 400 + l] = p + bv[0];
    return;
  }
  blk -= 800;
  { // 32 blocks: pgen h-dot = h_new . Wp[512:1024]
    int b = blk;
    __shared__ float red[256];
    float p = 0.f;
    for (int i = tid; i < 512; i += 256) p += h_new[b * 512 + i] * Wp[512 + i];
    red[tid] = p; __syncthreads();
    for (int s = 128; s > 0; s >>= 1){ if (tid < s) red[tid] += red[tid + s]; __syncthreads(); }
    if (tid == 0) pgen_hd[b] = red[0];
  }
}

// ---- fused: softmax(scores)*mask/renorm + attn/cov outputs + context + pgen ctx-dots + rowMS ----
__global__ __launch_bounds__(256) void k_attn_ctx(
    const float* __restrict__ scores, const float* __restrict__ mask,
    const float* __restrict__ cov_in, float* attn_out, float* cov_out,
    const unsigned short* __restrict__ enc_bf,
    float* __restrict__ ctx_out, float* ctxf_out, const float* __restrict__ Wp,
    float* __restrict__ pgen_cn, float* __restrict__ pgen_co,
    const float* __restrict__ tilems, float* __restrict__ rowMS)
{
  int b = blockIdx.x >> 3, ct = blockIdx.x & 7;
  int tid = threadIdx.x;
  __shared__ float at[400];
  __shared__ float red[512];
  float mx = -1e30f;
  for (int i = tid; i < 400; i += 256){ float s = scores[b * 400 + i]; at[i] = s; mx = fmaxf(mx, s); }
  red[tid] = mx; __syncthreads();
  for (int s = 128; s > 0; s >>= 1){ if (tid < s) red[tid] = fmaxf(red[tid], red[tid + s]); __syncthreads(); }
  mx = red[0]; __syncthreads();
  float sm = 0.f;
  for (int i = tid; i < 400; i += 256){ float e = __expf(at[i] - mx) * mask[b * 400 + i]; at[i] = e; sm += e; }
  red[tid] = sm; __syncthreads();
  for (int s = 128; s > 0; s >>= 1){ if (tid < s) red[tid] += red[tid + s]; __syncthreads(); }
  float inv = __builtin_amdgcn_rcpf(red[0]);
  __syncthreads();
  for (int i = tid; i < 400; i += 256){
    float a = at[i] * inv; at[i] = a;
    if (ct == 0){
      if (attn_out) attn_out[b * 400 + i] = a;
      float cv = (cov_in ? cov_in[b * 400 + i] : 0.f) + a;
      if (cov_out) cov_out[b * 400 + i] = cv;
    }
  }
  __syncthreads();
  // context for this block's 64 cols
  int colp = (tid & 31) * 2;
  int chunk = tid >> 5;
  const unsigned short* base = enc_bf + (size_t)b * 400 * 512 + ct * 64 + colp;
  float a0 = 0.f, a1 = 0.f;
  for (int i = 0; i < 50; i++){
    int l = chunk * 50 + i;
    unsigned int u = *(const unsigned int*)(base + (size_t)l * 512);
    float av = at[l];
    a0 += av * bf2f((unsigned short)(u & 0xffffu));
    a1 += av * bf2f((unsigned short)(u >> 16));
  }
  red[chunk * 64 + colp] = a0; red[chunk * 64 + colp + 1] = a1;
  __syncthreads();
  if (tid < 64){
    float s = 0.f;
    #pragma unroll
    for (int c = 0; c < 8; c++) s += red[c * 64 + tid];
    int col = ct * 64 + tid;
    ctx_out[b * 512 + col] = s;
    if (ctxf_out) ctxf_out[b * 512 + col] = s;
    float cn = s * Wp[col];
    float co = s * Wp[1280 + col];
    #pragma unroll
    for (int off = 32; off > 0; off >>= 1){ cn += __shfl_down(cn, off); co += __shfl_down(co, off); }
    if (tid == 0){ pgen_cn[b * 8 + ct] = cn; pgen_co[b * 8 + ct] = co; }
  }
  __syncthreads();
  if (ct == 0 && tilems != nullptr){ // reduce 500 tile partials -> rowMS
    float M = -1e30f;
    for (int i = tid; i < 500; i += 256) M = fmaxf(M, tilems[(i * 32 + b) * 2]);
    red[tid] = M; __syncthreads();
    for (int s = 128; s > 0; s >>= 1){ if (tid < s) red[tid] = fmaxf(red[tid], red[tid + s]); __syncthreads(); }
    M = red[0]; __syncthreads();
    float S = 0.f;
    for (int i = tid; i < 500; i += 256) S += tilems[(i * 32 + b) * 2 + 1] * __expf(tilems[(i * 32 + b) * 2] - M);
    red[tid] = S; __syncthreads();
    for (int s = 128; s > 0; s >>= 1){ if (tid < s) red[tid] += red[tid + s]; __syncthreads(); }
    if (tid == 0){ rowMS[b * 2] = M; rowMS[b * 2 + 1] = red[0]; }
  }
}

// ---------------- standalone final for the last step ----------------
__global__ __launch_bounds__(256) void k_fin(
    const float* __restrict__ logits, const float* __restrict__ rowMS,
    const float* __restrict__ pgen_hd, const float* __restrict__ pgen_cn,
    const float* __restrict__ pgen_co, const float* __restrict__ pgen_emb_t,
    const float* __restrict__ bp, float* __restrict__ final_t, float* __restrict__ pgens_t)
{
  final_dist_write(blockIdx.x, threadIdx.x, logits, rowMS, pgen_hd, pgen_cn, pgen_co,
                   pgen_emb_t, bp, final_t, pgens_t);
}

// ---------------- trailing scatter for the last step ----------------
__global__ __launch_bounds__(256) void k_scatter(
    const int* __restrict__ eidx, const float* __restrict__ attn_prev,
    const float* __restrict__ pgens_prev, float* __restrict__ final_prev)
{
  int i = blockIdx.x * 256 + threadIdx.x;
  if (i >= 12800) return;
  int b = i / 400;
  float wv = (1.f - pgens_prev[b]) * attn_prev[i];
  atomicAdd(final_prev + (size_t)b * VEXT + eidx[i], wv);
}

extern "C" void kernel_launch(void* const* d_in, const int* in_sizes, int n_in,
                              void* d_out, int out_size, void* d_ws, size_t ws_size,
                              hipStream_t stream) {
  const int*   dec_inp    = (const int*)d_in[0];
  const int*   eidx       = (const int*)d_in[1];
  const float* mask       = (const float*)d_in[2];
  const float* enc        = (const float*)d_in[4];
  const float* dec_hidden = (const float*)d_in[5];
  const float* embedding  = (const float*)d_in[6];
  const float* W1  = (const float*)d_in[7];
  const float* b1  = (const float*)d_in[8];
  const float* W2  = (const float*)d_in[9];
  const float* b2  = (const float*)d_in[10];
  const float* Wc  = (const float*)d_in[11];
  const float* Va  = (const float*)d_in[12];
  const float* bv  = (const float*)d_in[13];
  const float* Wg  = (const float*)d_in[14];
  const float* Ug  = (const float*)d_in[15];
  const float* bg  = (const float*)d_in[16];
  const float* Wout = (const float*)d_in[17];
  const float* bout = (const float*)d_in[18];
  const float* Wp  = (const float*)d_in[19];
  const float* bp  = (const float*)d_in[20];

  float* out    = (float*)d_out;
  float* final_ = out;                               // 40*32*32050
  float* attns  = out + (size_t)40 * 32 * VEXT;      // 40*32*400
  float* covs   = attns + 512000;
  float* hf     = covs + 512000;
  float* ctxf   = hf + 16384;
  float* pgens  = ctxf + 16384;

  char* wsb = (char*)d_ws; size_t off = 0;
  auto A = [&](size_t bytes)->char*{ char* p = wsb + off; off += (bytes + 255) & ~(size_t)255; return p; };
  float* logits   = (float*)A((size_t)32 * VV * 4);
  float* embW     = (float*)A((size_t)40 * 32 * 1536 * 4);
  float* tilems   = (float*)A(500 * 32 * 2 * 4);
  float* hbuf0    = (float*)A(65536);
  float* hbuf1    = (float*)A(65536);
  float* ctxbuf0  = (float*)A(65536);
  float* ctxbuf1  = (float*)A(65536);
  float* w1h      = (float*)A(65536);
  float* scores   = (float*)A(51200);
  float* rowMS    = (float*)A(256);
  float* pgen_hd  = (float*)A(128);
  float* pgen_cn  = (float*)A(1024);
  float* pgen_co0 = (float*)A(1024);
  float* pgen_co1 = (float*)A(1024);
  float* pgen_emb = (float*)A(40 * 32 * 4);
  unsigned short* h_bf   = (unsigned short*)A(32768);
  unsigned short* enc_bf = (unsigned short*)A((size_t)32 * 400 * 512 * 2);
  unsigned short* ef_bf  = (unsigned short*)A((size_t)32 * 400 * 512 * 2);
  unsigned short* W2T    = (unsigned short*)A(524288);
  unsigned short* W1T    = (unsigned short*)A(524288);
  unsigned short* WgT    = (unsigned short*)A(2359296);
  unsigned short* UgT    = (unsigned short*)A(1572864);
  unsigned short* WoutT  = (unsigned short*)A((size_t)VV * 512 * 2);
  float* hbuf[2]   = {hbuf0, hbuf1};
  float* ctxbuf[2] = {ctxbuf0, ctxbuf1};
  float* pgen_co[2] = {pgen_co0, pgen_co1};

  // ---- prologue ----
  k_prep<<<7856, 256, 0, stream>>>(Wout, Wg, Ug, W1, W2, enc, dec_hidden, dec_inp, embedding, Wp,
                                   WoutT, WgT, UgT, W1T, W2T, enc_bf, hbuf[0], h_bf, pgen_emb);
  k_embw<<<480, 256, 0, stream>>>(dec_inp, embedding, WgT, bg, embW);
  k_encfeat<<<1600, 256, 0, stream>>>(enc_bf, W2T, b2, ef_bf);
  k_gemm_h<<<8, 256, 0, stream>>>(h_bf, WoutT, bout, logits, W1T, b1, w1h, 0, tilems,
                                  eidx, nullptr, nullptr, nullptr); // w1h(h0) only
  k_score<<<832, 256, 0, stream>>>(ef_bf, w1h, Wc, Va, bv, nullptr, scores,
                                   hbuf[0], Wp, pgen_hd);
  // "attn_ctx(-1)": attn0/cov0 -> outputs[0], ctx0 -> ctxbuf[0], co[1] = ctx0-old-dot
  k_attn_ctx<<<256, 256, 0, stream>>>(scores, mask, nullptr, attns, covs, enc_bf,
                                      ctxbuf[0], nullptr, Wp, pgen_cn, pgen_co[1],
                                      nullptr, rowMS);

  // ---- decode loop ----
  for (int t = 0; t < 40; t++){
    int p = t & 1;
    // gru(t): ctx(t-1)=ctxbuf[p], h(t-1)=hbuf[p] -> h(t)=hbuf[p^1]; hosts final(t-1)
    k_gru<<<(t >= 1 ? 520 : 8), 256, 0, stream>>>(
        ctxbuf[p], hbuf[p], embW + (size_t)t * 32 * 1536, WgT, UgT,
        hbuf[p ^ 1], h_bf, (t == 39) ? hf : nullptr,
        logits, rowMS, pgen_hd, pgen_cn, pgen_co[t & 1],
        (t >= 1) ? pgen_emb + (t - 1) * 32 : pgen_emb, bp,
        (t >= 1) ? final_ + (size_t)(t - 1) * 32 * VEXT : nullptr,
        (t >= 1) ? pgens + (t - 1) * 32 : nullptr);
    // gemm(t): logits/w1h of h(t); hosts scatter(t-1)
    k_gemm_h<<<(t >= 1 ? 558 : 508), 256, 0, stream>>>(
        h_bf, WoutT, bout, logits, W1T, b1, w1h, 500, tilems,
        eidx,
        (t >= 1) ? attns + (size_t)(t - 1) * 12800 : nullptr,
        (t >= 1) ? pgens + (t - 1) * 32 : nullptr,
        (t >= 1) ? final_ + (size_t)(t - 1) * 32 * VEXT : nullptr);
    // score(t): uses cov(t)=covs[t], h(t)
    k_score<<<832, 256, 0, stream>>>(ef_bf, w1h, Wc, Va, bv, covs + (size_t)t * 12800, scores,
                                     hbuf[p ^ 1], Wp, pgen_hd);
    // attn_ctx(t): attn(t)->attns[t+1], cov(t+1)->covs[t+1], ctx(t)->ctxbuf[p^1], rowMS(t)
    k_attn_ctx<<<256, 256, 0, stream>>>(scores, mask, covs + (size_t)t * 12800,
                                        (t < 39) ? attns + (size_t)(t + 1) * 12800 : nullptr,
                                        (t < 39) ? covs + (size_t)(t + 1) * 12800 : nullptr,
                                        enc_bf, ctxbuf[p ^ 1], (t == 39) ? ctxf : nullptr, Wp,
                                        pgen_cn, pgen_co[t & 1], tilems, rowMS);
  }
  // ---- epilogue: final(39) + scatter(39) ----
  k_fin<<<512, 256, 0, stream>>>(logits, rowMS, pgen_hd, pgen_cn, pgen_co[0],
                                 pgen_emb + 39 * 32, bp,
                                 final_ + (size_t)39 * 32 * VEXT, pgens + 39 * 32);
  k_scatter<<<50, 256, 0, stream>>>(eidx, attns + (size_t)39 * 12800, pgens + 39 * 32,
                                    final_ + (size_t)39 * 32 * VEXT);
}